// Round 2
// baseline (464.846 us; speedup 1.0000x reference)
//
#include <hip/hip_runtime.h>
#include <math.h>

// Problem constants
#define BN 32768
#define DN 512
#define SN 32
#define LN 8
#define KN 256
#define N2 65536   // 2*BN
#define SPLIT 8    // blocks per group in k1

typedef __attribute__((ext_vector_type(8))) short bf16x8;
typedef __attribute__((ext_vector_type(4))) float f32x4;

// workspace layout (byte offsets)
#define OFF_XBF     0ull            // ushort[N2*DN]            67108864
#define OFF_PART    67108864ull     // float[SPLIT*KN*DN]        4194304
#define OFF_CENTB   71303168ull     // ushort[KN*DN]              262144
#define OFF_XNORM   71565312ull     // float[N2]                  262144
#define OFF_PERM    71827456ull     // int[BN]                    131072
#define OFF_BASE    71958528ull     // int[KN+1]                    1028
#define OFF_OFFW    71959556ull     // int[KN]  (zero-based cursor) 1024
#define OFF_COUNTS  71960580ull     // int[KN]                      1024
#define OFF_SUMQ    71961604ull     // float[KN]                    1024
#define OFF_CNORM   71962628ull     // float[KN]                    1024
#define OFF_LOSS    71963652ull     // float[1]                        4
#define OFF_BARS    71963656ull     // uint[6]: {cnt,flag} x3          24
#define ZERO_OFF    OFF_OFFW
#define ZERO_BYTES  (71963680ull - OFF_OFFW)   // 4124

__device__ __forceinline__ float atomAddF(float* p, float v) {
  return unsafeAtomicAdd(p, v);   // hw global_atomic_add_f32 (device scope)
}

// single-use device-wide barrier: arrive (agent-scope RMW) + spin on flag.
// Legal only when ALL blocks of the grid are co-resident (checked per-kernel).
__device__ __forceinline__ void gridbar1(unsigned* cnt, unsigned* flag, unsigned nblocks) {
  __syncthreads();
  if (threadIdx.x == 0) {
    __threadfence();
    unsigned a = __hip_atomic_fetch_add(cnt, 1u, __ATOMIC_ACQ_REL,
                                        __HIP_MEMORY_SCOPE_AGENT);
    if (a + 1u == nblocks) {
      __hip_atomic_store(flag, 1u, __ATOMIC_RELEASE, __HIP_MEMORY_SCOPE_AGENT);
    } else {
      while (!__hip_atomic_load(flag, __ATOMIC_ACQUIRE, __HIP_MEMORY_SCOPE_AGENT)) {
        __builtin_amdgcn_s_sleep(2);
      }
    }
    __threadfence();
  }
  __syncthreads();
}

__device__ __forceinline__ ushort f2bf(float x) {
  union { float f; unsigned u; } v; v.f = x;
  unsigned u = v.u;
  unsigned r = (u + 0x7fffu + ((u >> 16) & 1u)) >> 16;  // RNE
  return (ushort)r;
}

__device__ __forceinline__ float bf2f(ushort x) {
  union { unsigned u; float f; } v; v.u = ((unsigned)x) << 16;
  return v.f;
}

// async 16B/lane global->LDS DMA (lands at lds base + lane*16)
__device__ __forceinline__ void async16(const void* g, void* l) {
  __builtin_amdgcn_global_load_lds(
      (const __attribute__((address_space(1))) unsigned int*)g,
      (__attribute__((address_space(3))) unsigned int*)l, 16, 0, 0);
}

// ---- k0: fused gid/hist + scan + scatter (32 blocks, hand grid-barrier) ----
// phase1: per-block LDS hist + device atomics to counts; barrier;
// phase2: every block redundantly scans counts (atomics-only crosses the
//         barrier); block 0 persists base[] for k1; scatter via cursor offw.
__global__ __launch_bounds__(256) void k0_all(const int* __restrict__ subject,
    const int* __restrict__ labels, int* __restrict__ counts, int* __restrict__ base,
    int* __restrict__ offw, int* __restrict__ perm, unsigned* __restrict__ bars) {
  __shared__ int lhist[KN];
  __shared__ int sh[KN];
  __shared__ int lbase[KN];
  const int t = threadIdx.x;
  const int b0 = blockIdx.x * 1024;
  lhist[t] = 0;
  __syncthreads();
  int g[4], lr[4];
#pragma unroll
  for (int k = 0; k < 4; ++k) {
    const int b = b0 + k * 256 + t;
    g[k] = subject[b] * LN + labels[b];
    lr[k] = atomicAdd(&lhist[g[k]], 1);
  }
  __syncthreads();
  const int h = lhist[t];
  if (h) atomicAdd(&counts[t], 2 * h);
  gridbar1(&bars[0], &bars[1], 32);
  const int rows = ((int)__hip_atomic_load((unsigned*)&counts[t], __ATOMIC_RELAXED,
                                           __HIP_MEMORY_SCOPE_AGENT)) >> 1;
  sh[t] = rows;
  __syncthreads();
  for (int d = 1; d < 256; d <<= 1) {
    int add = (t >= d) ? sh[t - d] : 0;
    __syncthreads();
    sh[t] += add;
    __syncthreads();
  }
  const int excl = sh[t] - rows;
  if (blockIdx.x == 0) {
    base[t] = excl;
    if (t == 255) base[256] = sh[255];
  }
  if (h) lbase[t] = excl + atomicAdd(&offw[t], h);
  __syncthreads();
#pragma unroll
  for (int k = 0; k < 4; ++k)
    perm[lbase[g[k]] + lr[k]] = b0 + k * 256 + t;
}

// ---- k1: sorted segment-reduce group sums + f32->bf16 conversion + row norms ----
// Wave-parallel: each wave owns an independent row stream (32 streams/group).
// xnorm[row] = sum of (bf16-rounded x)^2 per view-row -> feeds fused distance in k5.
__global__ __launch_bounds__(256) void k1_sums(const float* __restrict__ X,
    const int* __restrict__ perm, const int* __restrict__ base,
    ushort* __restrict__ Xb, float* __restrict__ partial, float* __restrict__ xnorm) {
  __shared__ float buf[4 * 512];
  const int g = blockIdx.x >> 3;
  const int s = blockIdx.x & (SPLIT - 1);
  const int t = threadIdx.x;
  const int w = t >> 6;
  const int lane = t & 63;
  const int start = base[g], end = base[g + 1];
  const int vs = s * 4 + w;              // stream 0..31

  float4 a0 = {0.f, 0.f, 0.f, 0.f};
  float4 a1 = {0.f, 0.f, 0.f, 0.f};

  int i = start + vs;
  if (i < end) {
    int idx = perm[i];
    const float* bp = X + (size_t)idx * 1024 + lane * 4;
    float4 x0 = *(const float4*)(bp);
    float4 x1 = *(const float4*)(bp + 256);
    float4 x2 = *(const float4*)(bp + 512);
    float4 x3 = *(const float4*)(bp + 768);
    while (true) {
      const int inext = i + 32;
      int idxn = idx;
      float4 y0 = x0, y1 = x1, y2 = x2, y3 = x3;
      if (inext < end) {
        idxn = perm[inext];
        const float* bn = X + (size_t)idxn * 1024 + lane * 4;
        y0 = *(const float4*)(bn);
        y1 = *(const float4*)(bn + 256);
        y2 = *(const float4*)(bn + 512);
        y3 = *(const float4*)(bn + 768);
      }
      a0.x += x0.x + x2.x; a0.y += x0.y + x2.y;
      a0.z += x0.z + x2.z; a0.w += x0.w + x2.w;
      a1.x += x1.x + x3.x; a1.y += x1.y + x3.y;
      a1.z += x1.z + x3.z; a1.w += x1.w + x3.w;
      ushort4 u0 = (ushort4){f2bf(x0.x), f2bf(x0.y), f2bf(x0.z), f2bf(x0.w)};
      ushort4 u1 = (ushort4){f2bf(x1.x), f2bf(x1.y), f2bf(x1.z), f2bf(x1.w)};
      ushort4 u2 = (ushort4){f2bf(x2.x), f2bf(x2.y), f2bf(x2.z), f2bf(x2.w)};
      ushort4 u3 = (ushort4){f2bf(x3.x), f2bf(x3.y), f2bf(x3.z), f2bf(x3.w)};
      ushort* xb0 = Xb + (size_t)idx * DN + lane * 4;
      ushort* xb1 = Xb + (size_t)(idx + BN) * DN + lane * 4;
      *(ushort4*)(xb0)       = u0;
      *(ushort4*)(xb0 + 256) = u1;
      *(ushort4*)(xb1)       = u2;
      *(ushort4*)(xb1 + 256) = u3;
      // per-view-row squared norms of the bf16-rounded values
      float n0, n1, tv;
      tv = bf2f(u0.x); n0  = tv * tv;  tv = bf2f(u0.y); n0 += tv * tv;
      tv = bf2f(u0.z); n0 += tv * tv;  tv = bf2f(u0.w); n0 += tv * tv;
      tv = bf2f(u1.x); n0 += tv * tv;  tv = bf2f(u1.y); n0 += tv * tv;
      tv = bf2f(u1.z); n0 += tv * tv;  tv = bf2f(u1.w); n0 += tv * tv;
      tv = bf2f(u2.x); n1  = tv * tv;  tv = bf2f(u2.y); n1 += tv * tv;
      tv = bf2f(u2.z); n1 += tv * tv;  tv = bf2f(u2.w); n1 += tv * tv;
      tv = bf2f(u3.x); n1 += tv * tv;  tv = bf2f(u3.y); n1 += tv * tv;
      tv = bf2f(u3.z); n1 += tv * tv;  tv = bf2f(u3.w); n1 += tv * tv;
#pragma unroll
      for (int off = 32; off > 0; off >>= 1) {
        n0 += __shfl_down(n0, off, 64);
        n1 += __shfl_down(n1, off, 64);
      }
      if (lane == 0) { xnorm[idx] = n0; xnorm[idx + BN] = n1; }
      if (inext >= end) break;
      i = inext; idx = idxn; x0 = y0; x1 = y1; x2 = y2; x3 = y3;
    }
  }
  *(float4*)&buf[w * 512 + lane * 4] = a0;
  *(float4*)&buf[w * 512 + 256 + lane * 4] = a1;
  __syncthreads();
  if (t < 128) {
    float4 r = {0.f, 0.f, 0.f, 0.f};
#pragma unroll
    for (int ww = 0; ww < 4; ++ww) {
      float4 v = *(float4*)&buf[ww * 512 + t * 4];
      r.x += v.x; r.y += v.y; r.z += v.z; r.w += v.w;
    }
    *(float4*)&partial[((size_t)s * KN + g) * DN + t * 4] = r;
  }
}

// ---- k1b: reduce split partials -> bf16 centroids + centroid norms ----
// (each block covers 256 consecutive [g][d] -> g is constant per block)
__global__ __launch_bounds__(256) void k1b_cent(const float* __restrict__ partial,
    const int* __restrict__ counts, ushort* __restrict__ centB,
    float* __restrict__ cnorm) {
  __shared__ float wsum[4];
  const int t = threadIdx.x;
  const int w = t >> 6;
  const int lane = t & 63;
  const int i = blockIdx.x * 256 + t;   // over KN*DN, [g][d]
  const int g = i >> 9;
  float ss = 0.f;
#pragma unroll
  for (int s = 0; s < SPLIT; ++s) ss += partial[(size_t)s * (KN * DN) + i];
  const ushort cb = f2bf(ss / (float)counts[g]);
  centB[i] = cb;
  const float cf = bf2f(cb);
  float c2 = cf * cf;
#pragma unroll
  for (int off = 32; off > 0; off >>= 1) c2 += __shfl_down(c2, off, 64);
  if (lane == 0) wsum[w] = c2;
  __syncthreads();
  if (t == 0) atomAddF(&cnorm[g], wsum[0] + wsum[1] + wsum[2] + wsum[3]);
}

// ---- k5: MFMA GEMM + fused distance (k3) + density (k4) + softmax loss +
//          final mean (k6), hand grid-barrier x2 ----
// dist^2 = ||bx||^2 - 2*(bx . bc) + ||bc||^2 : the middle term is the GEMM's
// own-group column, already in the accumulator -> k3's 64MB Xb re-read is gone.
// Co-residency: 512 blocks, (256,2) -> VGPR<=256 => >=2 blocks/CU; LDS 50KB
// => 3/CU; 2 blocks/CU x 256 CU = 512 = grid. All blocks resident -> barrier ok.
// NOTE: (256,2) is required — (256,3) caps VGPRs < 128 acc + staging (spills).
#define TAB (128 * 128)   // A tile bytes
#define TBB (256 * 128)   // B tile bytes
__global__ __launch_bounds__(256, 2) void k5_mfma(const ushort* __restrict__ Xb,
    const ushort* __restrict__ centB, const int* __restrict__ subject,
    const int* __restrict__ labels, const float* __restrict__ xnorm,
    const float* __restrict__ cnorm, const int* __restrict__ counts,
    float* __restrict__ sumq, float* __restrict__ losssum,
    float* __restrict__ out, unsigned* __restrict__ bars) {
  __shared__ char smem[TAB + TBB + 1024];
  char* ldsA = smem;                 // [128 rows][128B, swizzled]
  char* ldsB = smem + TAB;           // [256 rows][128B, swizzled]
  float* maxbuf = (float*)smem;      // epilogue aliases ldsA: [4][128]
  float* gmax = (float*)(smem + 2048);    // [128]
  float* ebuf = (float*)(smem + 2560);    // [4][128]
  float* zbuf = (float*)(smem + 4608);    // [4][128]
  float* sv   = (float*)(smem + 9216);    // [256] density scratch
  float* stv  = (float*)(smem + 10240);   // [256] density sort
  float* dinv = (float*)(smem + 11264);   // [256] 1/density
  int* labs = (int*)(smem + TAB + TBB);
  int* subs = labs + 128;

  const int t = threadIdx.x;
  const int w = t >> 6;
  const int lane = t & 63;
  const int quad = lane >> 4;
  const int n16 = lane & 15;
  const int li = lane >> 3;          // row within an 8-row DMA chunk
  const int lc = lane & 7;           // lds slot chunk
  const int srcc = lc ^ li;          // swizzled source chunk
  const int rowbase = blockIdx.x * 128;

  if (t < 128) {
    int b = (rowbase + t) & (BN - 1);
    labs[t] = labels[b];
    subs[t] = subject[b];
  }

  f32x4 acc[8][4];
#pragma unroll
  for (int mt = 0; mt < 8; ++mt)
#pragma unroll
    for (int nt = 0; nt < 4; ++nt) acc[mt][nt] = (f32x4){0.f, 0.f, 0.f, 0.f};

  const ushort* Arow = Xb + (size_t)rowbase * DN;

  for (int k0 = 0; k0 < DN; k0 += 64) {
    __syncthreads();
#pragma unroll
    for (int q = 0; q < 4; ++q) {
      const int r0 = w * 32 + q * 8;
      async16(Arow + (size_t)(r0 + li) * DN + k0 + srcc * 8, ldsA + r0 * 128);
    }
#pragma unroll
    for (int q = 0; q < 8; ++q) {
      const int g0 = w * 64 + q * 8;
      async16(centB + (size_t)(g0 + li) * DN + k0 + srcc * 8, ldsB + g0 * 128);
    }
    __syncthreads();
#pragma unroll
    for (int s = 0; s < 2; ++s) {
      const int csw = ((s * 4 + quad) ^ (n16 & 7)) * 16;
      bf16x8 bfr[4];
#pragma unroll
      for (int nt = 0; nt < 4; ++nt) {
        int g = w * 64 + nt * 16 + n16;
        bfr[nt] = *(bf16x8*)(ldsB + g * 128 + csw);
      }
#pragma unroll
      for (int mt = 0; mt < 8; ++mt) {
        bf16x8 afr = *(bf16x8*)(ldsA + (mt * 16 + n16) * 128 + csw);
#pragma unroll
        for (int nt = 0; nt < 4; ++nt)
          acc[mt][nt] = __builtin_amdgcn_mfma_f32_16x16x32_bf16(afr, bfr[nt], acc[mt][nt], 0, 0, 0);
      }
    }
  }

  // ---- fused k3: own-group dot -> dist^(1/2) accumulation (1 thread/row) ----
#pragma unroll
  for (int mt = 0; mt < 8; ++mt) {
#pragma unroll
    for (int r = 0; r < 4; ++r) {
      const int row = mt * 16 + quad * 4 + r;
      const int g = subs[row] * LN + labs[row];
      if ((g >> 6) == w && (g & 15) == n16) {
        const int nt = (g >> 4) & 3;
        float dot = (nt == 0) ? acc[mt][0][r] : (nt == 1) ? acc[mt][1][r]
                  : (nt == 2) ? acc[mt][2][r] : acc[mt][3][r];
        float d2 = xnorm[rowbase + row] - 2.0f * dot + cnorm[g];
        atomAddF(&sumq[g], sqrtf(sqrtf(fmaxf(d2, 0.0f))));
      }
    }
  }
  gridbar1(&bars[2], &bars[3], 512);

  // ---- fused k4: density (redundant per block; thread t <-> group t) ----
  {
    const int cnt = counts[t];
    const bool valid = cnt > 1;
    const float sq = __hip_atomic_load(&sumq[t], __ATOMIC_RELAXED,
                                       __HIP_MEMORY_SCOPE_AGENT);
    float dens = 0.f;
    if (valid) dens = (sq / (float)cnt) / logf((float)cnt + 10.f);
    sv[t] = valid ? dens : -INFINITY;
    __syncthreads();
    for (int s2 = 128; s2 > 0; s2 >>= 1) {
      if (t < s2) sv[t] = fmaxf(sv[t], sv[t + s2]);
      __syncthreads();
    }
    const float dmax = sv[0];
    __syncthreads();
    const float d0 = valid ? dens : dmax;
    sv[t] = d0;
    __syncthreads();
    int rank = 0;
    for (int j = 0; j < 256; ++j) {
      float vj = sv[j];
      rank += (vj < d0) || (vj == d0 && j < t);
    }
    stv[rank] = d0;
    __syncthreads();
    const float q10 = 0.5f * (stv[25] + stv[26]);
    const float q90 = 0.5f * (stv[229] + stv[230]);
    const float dc = fminf(fmaxf(d0, q10), q90);
    sv[t] = dc;
    __syncthreads();
    for (int s2 = 128; s2 > 0; s2 >>= 1) {
      if (t < s2) sv[t] += sv[t + s2];
      __syncthreads();
    }
    dinv[t] = (sv[0] * (1.0f / 256.f)) / (0.1f * dc);
  }
  __syncthreads();

  float iv[4];
#pragma unroll
  for (int nt = 0; nt < 4; ++nt) iv[nt] = dinv[w * 64 + nt * 16 + n16];
  __syncthreads();

  // ---- epilogue: row max ----
#pragma unroll
  for (int mt = 0; mt < 8; ++mt) {
#pragma unroll
    for (int r = 0; r < 4; ++r) {
      float mm = -INFINITY;
#pragma unroll
      for (int nt = 0; nt < 4; ++nt) mm = fmaxf(mm, acc[mt][nt][r] * iv[nt]);
#pragma unroll
      for (int off = 1; off < 16; off <<= 1) mm = fmaxf(mm, __shfl_xor(mm, off, 64));
      if (n16 == 0) maxbuf[w * 128 + mt * 16 + quad * 4 + r] = mm;
    }
  }
  __syncthreads();
  if (t < 128)
    gmax[t] = fmaxf(fmaxf(maxbuf[t], maxbuf[128 + t]),
                    fmaxf(maxbuf[256 + t], maxbuf[384 + t]));
  __syncthreads();

#pragma unroll
  for (int mt = 0; mt < 8; ++mt) {
#pragma unroll
    for (int r = 0; r < 4; ++r) {
      const int row = mt * 16 + quad * 4 + r;
      const float gm = gmax[row];
      const int lab = labs[row];
      const int sub = subs[row];
      float e = 0.f, z = 0.f;
      if ((n16 & 7) == lab) {
#pragma unroll
        for (int nt = 0; nt < 4; ++nt) {
          int gdiv8 = w * 8 + nt * 2 + (n16 >> 3);
          if (gdiv8 != sub) {
            float svv = acc[mt][nt][r] * iv[nt] - gm;
            e += expf(svv);
            z += svv;
          }
        }
      }
#pragma unroll
      for (int off = 1; off < 16; off <<= 1) {
        e += __shfl_xor(e, off, 64);
        z += __shfl_xor(z, off, 64);
      }
      if (n16 == 0) {
        ebuf[w * 128 + row] = e;
        zbuf[w * 128 + row] = z;
      }
    }
  }
  __syncthreads();

  float lsum = 0.f;
  if (t < 128) {
    float e = ebuf[t] + ebuf[128 + t] + ebuf[256 + t] + ebuf[384 + t];
    float z = zbuf[t] + zbuf[128 + t] + zbuf[256 + t] + zbuf[384 + t];
    lsum = logf(225.f + e) - z * (1.0f / 31.0f);
  }
#pragma unroll
  for (int off = 32; off > 0; off >>= 1) lsum += __shfl_down(lsum, off, 64);
  if (lane == 0 && lsum != 0.f) atomAddF(losssum, lsum);

  // ---- fused k6: final mean ----
  gridbar1(&bars[4], &bars[5], 512);
  if (blockIdx.x == 0 && t == 0) {
    const float ls = __hip_atomic_load(losssum, __ATOMIC_RELAXED,
                                       __HIP_MEMORY_SCOPE_AGENT);
    out[0] = ls * (1.0f / (float)N2);
  }
}

extern "C" void kernel_launch(void* const* d_in, const int* in_sizes, int n_in,
                              void* d_out, int out_size, void* d_ws, size_t ws_size,
                              hipStream_t stream) {
  const float* X = (const float*)d_in[0];
  const int* subject = (const int*)d_in[1];
  const int* labels = (const int*)d_in[2];
  char* ws = (char*)d_ws;
  ushort* Xb = (ushort*)(ws + OFF_XBF);
  float* partial = (float*)(ws + OFF_PART);
  ushort* centB = (ushort*)(ws + OFF_CENTB);
  float* xnorm = (float*)(ws + OFF_XNORM);
  int* perm = (int*)(ws + OFF_PERM);
  int* basep = (int*)(ws + OFF_BASE);
  int* offw = (int*)(ws + OFF_OFFW);
  int* counts = (int*)(ws + OFF_COUNTS);
  float* sumq = (float*)(ws + OFF_SUMQ);
  float* cnorm = (float*)(ws + OFF_CNORM);
  float* losssum = (float*)(ws + OFF_LOSS);
  unsigned* bars = (unsigned*)(ws + OFF_BARS);

  hipMemsetAsync(ws + ZERO_OFF, 0, ZERO_BYTES, stream);
  k0_all<<<32, 256, 0, stream>>>(subject, labels, counts, basep, offw, perm, bars);
  k1_sums<<<KN * SPLIT, 256, 0, stream>>>(X, perm, basep, Xb, partial, xnorm);
  k1b_cent<<<(KN * DN) / 256, 256, 0, stream>>>(partial, counts, centB, cnorm);
  k5_mfma<<<512, 256, 0, stream>>>(Xb, centB, subject, labels, xnorm, cnorm,
                                   counts, sumq, losssum, (float*)d_out, bars);
}

// Round 3
// 388.270 us; speedup vs baseline: 1.1972x; 1.1972x over previous
//
#include <hip/hip_runtime.h>
#include <math.h>

// Problem constants
#define BN 32768
#define DN 512
#define SN 32
#define LN 8
#define KN 256
#define N2 65536   // 2*BN
#define SPLIT 8    // blocks per group in k1

typedef __attribute__((ext_vector_type(8))) short bf16x8;
typedef __attribute__((ext_vector_type(4))) float f32x4;

// workspace layout (byte offsets)
#define OFF_XBF     0ull            // ushort[N2*DN]            67108864
#define OFF_PART    67108864ull     // float[SPLIT*KN*DN]        4194304
#define OFF_CENTB   71303168ull     // ushort[KN*DN]              262144
#define OFF_XNORM   71565312ull     // float[N2]                  262144
#define OFF_PERM    71827456ull     // int[BN]                    131072
#define OFF_BASE    71958528ull     // int[KN+1]                    1028
#define OFF_OFFW    71959556ull     // int[KN]  (zero-based cursor) 1024
#define OFF_COUNTS  71960580ull     // int[KN]                      1024
#define OFF_SUMQ    71961604ull     // float[KN]                    1024
#define OFF_CNORM   71962628ull     // float[KN]                    1024
#define OFF_LOSS    71963652ull     // float[1]                        4
#define OFF_BARS    71963656ull     // uint[6]: {cnt,flag}x2 + done    24
#define ZERO_OFF    OFF_OFFW
#define ZERO_BYTES  (71963680ull - OFF_OFFW)   // 4124

__device__ __forceinline__ float atomAddF(float* p, float v) {
  return unsafeAtomicAdd(p, v);   // hw global_atomic_add_f32 (coherence point)
}

// Relaxed device-wide barrier. NO threadfence / acquire / release: every value
// crossing this barrier is written by device-scope atomics (performed at the
// coherence point) and read back with agent-scope atomic loads (L1/L2 bypass),
// so no cache-wide wbl2/inv maintenance is needed — that was R2's 170us stall.
// All waves drain their own outstanding atomics (vmcnt) BEFORE the workgroup
// barrier, so thread 0's arrive-RMW globally orders the whole block's atomics.
// Legal only when all blocks co-resident (32-block k0; 512-block k5 @ 2/CU).
__device__ __forceinline__ void gridbar_relaxed(unsigned* cnt, unsigned* flag,
                                                unsigned nblocks) {
  asm volatile("s_waitcnt vmcnt(0)" ::: "memory");
  __syncthreads();
  if (threadIdx.x == 0) {
    unsigned a = __hip_atomic_fetch_add(cnt, 1u, __ATOMIC_RELAXED,
                                        __HIP_MEMORY_SCOPE_AGENT);
    if (a + 1u == nblocks) {
      __hip_atomic_store(flag, 1u, __ATOMIC_RELAXED, __HIP_MEMORY_SCOPE_AGENT);
    } else {
      while (!__hip_atomic_load(flag, __ATOMIC_RELAXED, __HIP_MEMORY_SCOPE_AGENT))
        __builtin_amdgcn_s_sleep(16);
    }
  }
  __syncthreads();
}

__device__ __forceinline__ ushort f2bf(float x) {
  union { float f; unsigned u; } v; v.f = x;
  unsigned u = v.u;
  unsigned r = (u + 0x7fffu + ((u >> 16) & 1u)) >> 16;  // RNE
  return (ushort)r;
}

__device__ __forceinline__ float bf2f(ushort x) {
  union { unsigned u; float f; } v; v.u = ((unsigned)x) << 16;
  return v.f;
}

// async 16B/lane global->LDS DMA (lands at lds base + lane*16)
__device__ __forceinline__ void async16(const void* g, void* l) {
  __builtin_amdgcn_global_load_lds(
      (const __attribute__((address_space(1))) unsigned int*)g,
      (__attribute__((address_space(3))) unsigned int*)l, 16, 0, 0);
}

// ---- k0: fused gid/hist + scan + scatter (32 blocks, relaxed grid-barrier) ----
__global__ __launch_bounds__(256) void k0_all(const int* __restrict__ subject,
    const int* __restrict__ labels, int* __restrict__ counts, int* __restrict__ base,
    int* __restrict__ offw, int* __restrict__ perm, unsigned* __restrict__ bars) {
  __shared__ int lhist[KN];
  __shared__ int sh[KN];
  __shared__ int lbase[KN];
  const int t = threadIdx.x;
  const int b0 = blockIdx.x * 1024;
  lhist[t] = 0;
  __syncthreads();
  int g[4], lr[4];
#pragma unroll
  for (int k = 0; k < 4; ++k) {
    const int b = b0 + k * 256 + t;
    g[k] = subject[b] * LN + labels[b];
    lr[k] = atomicAdd(&lhist[g[k]], 1);
  }
  __syncthreads();
  const int h = lhist[t];
  if (h) atomicAdd(&counts[t], 2 * h);
  gridbar_relaxed(&bars[0], &bars[1], 32);
  const int rows = ((int)__hip_atomic_load((unsigned*)&counts[t], __ATOMIC_RELAXED,
                                           __HIP_MEMORY_SCOPE_AGENT)) >> 1;
  sh[t] = rows;
  __syncthreads();
  for (int d = 1; d < 256; d <<= 1) {
    int add = (t >= d) ? sh[t - d] : 0;
    __syncthreads();
    sh[t] += add;
    __syncthreads();
  }
  const int excl = sh[t] - rows;
  if (blockIdx.x == 0) {
    base[t] = excl;
    if (t == 255) base[256] = sh[255];
  }
  if (h) lbase[t] = excl + atomicAdd(&offw[t], h);
  __syncthreads();
#pragma unroll
  for (int k = 0; k < 4; ++k)
    perm[lbase[g[k]] + lr[k]] = b0 + k * 256 + t;
}

// ---- k1: sorted segment-reduce group sums + f32->bf16 conversion + row norms ----
// Wave-parallel: each wave owns an independent row stream (32 streams/group).
// xnorm[row] = sum of (bf16-rounded x)^2 per view-row -> feeds fused distance in k5.
__global__ __launch_bounds__(256) void k1_sums(const float* __restrict__ X,
    const int* __restrict__ perm, const int* __restrict__ base,
    ushort* __restrict__ Xb, float* __restrict__ partial, float* __restrict__ xnorm) {
  __shared__ float buf[4 * 512];
  const int g = blockIdx.x >> 3;
  const int s = blockIdx.x & (SPLIT - 1);
  const int t = threadIdx.x;
  const int w = t >> 6;
  const int lane = t & 63;
  const int start = base[g], end = base[g + 1];
  const int vs = s * 4 + w;              // stream 0..31

  float4 a0 = {0.f, 0.f, 0.f, 0.f};
  float4 a1 = {0.f, 0.f, 0.f, 0.f};

  int i = start + vs;
  if (i < end) {
    int idx = perm[i];
    const float* bp = X + (size_t)idx * 1024 + lane * 4;
    float4 x0 = *(const float4*)(bp);
    float4 x1 = *(const float4*)(bp + 256);
    float4 x2 = *(const float4*)(bp + 512);
    float4 x3 = *(const float4*)(bp + 768);
    while (true) {
      const int inext = i + 32;
      int idxn = idx;
      float4 y0 = x0, y1 = x1, y2 = x2, y3 = x3;
      if (inext < end) {
        idxn = perm[inext];
        const float* bn = X + (size_t)idxn * 1024 + lane * 4;
        y0 = *(const float4*)(bn);
        y1 = *(const float4*)(bn + 256);
        y2 = *(const float4*)(bn + 512);
        y3 = *(const float4*)(bn + 768);
      }
      a0.x += x0.x + x2.x; a0.y += x0.y + x2.y;
      a0.z += x0.z + x2.z; a0.w += x0.w + x2.w;
      a1.x += x1.x + x3.x; a1.y += x1.y + x3.y;
      a1.z += x1.z + x3.z; a1.w += x1.w + x3.w;
      ushort4 u0 = (ushort4){f2bf(x0.x), f2bf(x0.y), f2bf(x0.z), f2bf(x0.w)};
      ushort4 u1 = (ushort4){f2bf(x1.x), f2bf(x1.y), f2bf(x1.z), f2bf(x1.w)};
      ushort4 u2 = (ushort4){f2bf(x2.x), f2bf(x2.y), f2bf(x2.z), f2bf(x2.w)};
      ushort4 u3 = (ushort4){f2bf(x3.x), f2bf(x3.y), f2bf(x3.z), f2bf(x3.w)};
      ushort* xb0 = Xb + (size_t)idx * DN + lane * 4;
      ushort* xb1 = Xb + (size_t)(idx + BN) * DN + lane * 4;
      *(ushort4*)(xb0)       = u0;
      *(ushort4*)(xb0 + 256) = u1;
      *(ushort4*)(xb1)       = u2;
      *(ushort4*)(xb1 + 256) = u3;
      // per-view-row squared norms of the bf16-rounded values
      float n0, n1, tv;
      tv = bf2f(u0.x); n0  = tv * tv;  tv = bf2f(u0.y); n0 += tv * tv;
      tv = bf2f(u0.z); n0 += tv * tv;  tv = bf2f(u0.w); n0 += tv * tv;
      tv = bf2f(u1.x); n0 += tv * tv;  tv = bf2f(u1.y); n0 += tv * tv;
      tv = bf2f(u1.z); n0 += tv * tv;  tv = bf2f(u1.w); n0 += tv * tv;
      tv = bf2f(u2.x); n1  = tv * tv;  tv = bf2f(u2.y); n1 += tv * tv;
      tv = bf2f(u2.z); n1 += tv * tv;  tv = bf2f(u2.w); n1 += tv * tv;
      tv = bf2f(u3.x); n1 += tv * tv;  tv = bf2f(u3.y); n1 += tv * tv;
      tv = bf2f(u3.z); n1 += tv * tv;  tv = bf2f(u3.w); n1 += tv * tv;
#pragma unroll
      for (int off = 32; off > 0; off >>= 1) {
        n0 += __shfl_down(n0, off, 64);
        n1 += __shfl_down(n1, off, 64);
      }
      if (lane == 0) { xnorm[idx] = n0; xnorm[idx + BN] = n1; }
      if (inext >= end) break;
      i = inext; idx = idxn; x0 = y0; x1 = y1; x2 = y2; x3 = y3;
    }
  }
  *(float4*)&buf[w * 512 + lane * 4] = a0;
  *(float4*)&buf[w * 512 + 256 + lane * 4] = a1;
  __syncthreads();
  if (t < 128) {
    float4 r = {0.f, 0.f, 0.f, 0.f};
#pragma unroll
    for (int ww = 0; ww < 4; ++ww) {
      float4 v = *(float4*)&buf[ww * 512 + t * 4];
      r.x += v.x; r.y += v.y; r.z += v.z; r.w += v.w;
    }
    *(float4*)&partial[((size_t)s * KN + g) * DN + t * 4] = r;
  }
}

// ---- k1b: reduce split partials -> bf16 centroids + centroid norms ----
__global__ __launch_bounds__(256) void k1b_cent(const float* __restrict__ partial,
    const int* __restrict__ counts, ushort* __restrict__ centB,
    float* __restrict__ cnorm) {
  __shared__ float wsum[4];
  const int t = threadIdx.x;
  const int w = t >> 6;
  const int lane = t & 63;
  const int i = blockIdx.x * 256 + t;   // over KN*DN, [g][d]
  const int g = i >> 9;
  float ss = 0.f;
#pragma unroll
  for (int s = 0; s < SPLIT; ++s) ss += partial[(size_t)s * (KN * DN) + i];
  const ushort cb = f2bf(ss / (float)counts[g]);
  centB[i] = cb;
  const float cf = bf2f(cb);
  float c2 = cf * cf;
#pragma unroll
  for (int off = 32; off > 0; off >>= 1) c2 += __shfl_down(c2, off, 64);
  if (lane == 0) wsum[w] = c2;
  __syncthreads();
  if (t == 0) atomAddF(&cnorm[g], wsum[0] + wsum[1] + wsum[2] + wsum[3]);
}

// ---- k5: MFMA GEMM + fused distance (k3) + density (k4) + softmax loss +
//          final mean (k6). ONE relaxed grid-barrier + last-block-out. ----
// dist^2 = ||bx||^2 - 2*(bx . bc) + ||bc||^2 : the middle term is the GEMM's
// own-group column, already in the accumulator -> k3's 64MB Xb re-read is gone.
// Co-residency: 512 blocks, (256,2) -> 2 blocks/CU x 256 CU = 512 = grid.
// NOTE: (256,2) is required — (256,3) caps VGPRs < 128 acc + staging (spills).
#define TAB (128 * 128)   // A tile bytes
#define TBB (256 * 128)   // B tile bytes
__global__ __launch_bounds__(256, 2) void k5_mfma(const ushort* __restrict__ Xb,
    const ushort* __restrict__ centB, const int* __restrict__ subject,
    const int* __restrict__ labels, const float* __restrict__ xnorm,
    const float* __restrict__ cnorm, const int* __restrict__ counts,
    float* __restrict__ sumq, float* __restrict__ losssum,
    float* __restrict__ out, unsigned* __restrict__ bars) {
  __shared__ char smem[TAB + TBB + 1024];
  char* ldsA = smem;                 // [128 rows][128B, swizzled]
  char* ldsB = smem + TAB;           // [256 rows][128B, swizzled]
  float* maxbuf = (float*)smem;      // epilogue aliases ldsA: [4][128]
  float* gmax = (float*)(smem + 2048);    // [128]
  float* ebuf = (float*)(smem + 2560);    // [4][128]
  float* zbuf = (float*)(smem + 4608);    // [4][128]
  float* sv   = (float*)(smem + 9216);    // [256] density scratch
  float* stv  = (float*)(smem + 10240);   // [256] density sort
  float* dinv = (float*)(smem + 11264);   // [256] 1/density
  int* labs = (int*)(smem + TAB + TBB);
  int* subs = labs + 128;

  const int t = threadIdx.x;
  const int w = t >> 6;
  const int lane = t & 63;
  const int quad = lane >> 4;
  const int n16 = lane & 15;
  const int li = lane >> 3;          // row within an 8-row DMA chunk
  const int lc = lane & 7;           // lds slot chunk
  const int srcc = lc ^ li;          // swizzled source chunk
  const int rowbase = blockIdx.x * 128;

  if (t < 128) {
    int b = (rowbase + t) & (BN - 1);
    labs[t] = labels[b];
    subs[t] = subject[b];
  }

  f32x4 acc[8][4];
#pragma unroll
  for (int mt = 0; mt < 8; ++mt)
#pragma unroll
    for (int nt = 0; nt < 4; ++nt) acc[mt][nt] = (f32x4){0.f, 0.f, 0.f, 0.f};

  const ushort* Arow = Xb + (size_t)rowbase * DN;

  for (int k0 = 0; k0 < DN; k0 += 64) {
    __syncthreads();
#pragma unroll
    for (int q = 0; q < 4; ++q) {
      const int r0 = w * 32 + q * 8;
      async16(Arow + (size_t)(r0 + li) * DN + k0 + srcc * 8, ldsA + r0 * 128);
    }
#pragma unroll
    for (int q = 0; q < 8; ++q) {
      const int g0 = w * 64 + q * 8;
      async16(centB + (size_t)(g0 + li) * DN + k0 + srcc * 8, ldsB + g0 * 128);
    }
    __syncthreads();
#pragma unroll
    for (int s = 0; s < 2; ++s) {
      const int csw = ((s * 4 + quad) ^ (n16 & 7)) * 16;
      bf16x8 bfr[4];
#pragma unroll
      for (int nt = 0; nt < 4; ++nt) {
        int g = w * 64 + nt * 16 + n16;
        bfr[nt] = *(bf16x8*)(ldsB + g * 128 + csw);
      }
#pragma unroll
      for (int mt = 0; mt < 8; ++mt) {
        bf16x8 afr = *(bf16x8*)(ldsA + (mt * 16 + n16) * 128 + csw);
#pragma unroll
        for (int nt = 0; nt < 4; ++nt)
          acc[mt][nt] = __builtin_amdgcn_mfma_f32_16x16x32_bf16(afr, bfr[nt], acc[mt][nt], 0, 0, 0);
      }
    }
  }

  // ---- fused k3: own-group dot -> dist^(1/2) accumulation (1 thread/row) ----
#pragma unroll
  for (int mt = 0; mt < 8; ++mt) {
#pragma unroll
    for (int r = 0; r < 4; ++r) {
      const int row = mt * 16 + quad * 4 + r;
      const int g = subs[row] * LN + labs[row];
      if ((g >> 6) == w && (g & 15) == n16) {
        const int nt = (g >> 4) & 3;
        float dot = (nt == 0) ? acc[mt][0][r] : (nt == 1) ? acc[mt][1][r]
                  : (nt == 2) ? acc[mt][2][r] : acc[mt][3][r];
        float d2 = xnorm[rowbase + row] - 2.0f * dot + cnorm[g];
        atomAddF(&sumq[g], sqrtf(sqrtf(fmaxf(d2, 0.0f))));
      }
    }
  }
  gridbar_relaxed(&bars[2], &bars[3], 512);

  // ---- fused k4: density (redundant per block; thread t <-> group t) ----
  {
    const int cnt = counts[t];
    const bool valid = cnt > 1;
    const float sq = __hip_atomic_load(&sumq[t], __ATOMIC_RELAXED,
                                       __HIP_MEMORY_SCOPE_AGENT);
    float dens = 0.f;
    if (valid) dens = (sq / (float)cnt) / logf((float)cnt + 10.f);
    sv[t] = valid ? dens : -INFINITY;
    __syncthreads();
    for (int s2 = 128; s2 > 0; s2 >>= 1) {
      if (t < s2) sv[t] = fmaxf(sv[t], sv[t + s2]);
      __syncthreads();
    }
    const float dmax = sv[0];
    __syncthreads();
    const float d0 = valid ? dens : dmax;
    sv[t] = d0;
    __syncthreads();
    int rank = 0;
    for (int j = 0; j < 256; ++j) {
      float vj = sv[j];
      rank += (vj < d0) || (vj == d0 && j < t);
    }
    stv[rank] = d0;
    __syncthreads();
    const float q10 = 0.5f * (stv[25] + stv[26]);
    const float q90 = 0.5f * (stv[229] + stv[230]);
    const float dc = fminf(fmaxf(d0, q10), q90);
    sv[t] = dc;
    __syncthreads();
    for (int s2 = 128; s2 > 0; s2 >>= 1) {
      if (t < s2) sv[t] += sv[t + s2];
      __syncthreads();
    }
    dinv[t] = (sv[0] * (1.0f / 256.f)) / (0.1f * dc);
  }
  __syncthreads();

  float iv[4];
#pragma unroll
  for (int nt = 0; nt < 4; ++nt) iv[nt] = dinv[w * 64 + nt * 16 + n16];
  __syncthreads();

  // ---- epilogue: row max ----
#pragma unroll
  for (int mt = 0; mt < 8; ++mt) {
#pragma unroll
    for (int r = 0; r < 4; ++r) {
      float mm = -INFINITY;
#pragma unroll
      for (int nt = 0; nt < 4; ++nt) mm = fmaxf(mm, acc[mt][nt][r] * iv[nt]);
#pragma unroll
      for (int off = 1; off < 16; off <<= 1) mm = fmaxf(mm, __shfl_xor(mm, off, 64));
      if (n16 == 0) maxbuf[w * 128 + mt * 16 + quad * 4 + r] = mm;
    }
  }
  __syncthreads();
  if (t < 128)
    gmax[t] = fmaxf(fmaxf(maxbuf[t], maxbuf[128 + t]),
                    fmaxf(maxbuf[256 + t], maxbuf[384 + t]));
  __syncthreads();

#pragma unroll
  for (int mt = 0; mt < 8; ++mt) {
#pragma unroll
    for (int r = 0; r < 4; ++r) {
      const int row = mt * 16 + quad * 4 + r;
      const float gm = gmax[row];
      const int lab = labs[row];
      const int sub = subs[row];
      float e = 0.f, z = 0.f;
      if ((n16 & 7) == lab) {
#pragma unroll
        for (int nt = 0; nt < 4; ++nt) {
          int gdiv8 = w * 8 + nt * 2 + (n16 >> 3);
          if (gdiv8 != sub) {
            float svv = acc[mt][nt][r] * iv[nt] - gm;
            e += expf(svv);
            z += svv;
          }
        }
      }
#pragma unroll
      for (int off = 1; off < 16; off <<= 1) {
        e += __shfl_xor(e, off, 64);
        z += __shfl_xor(z, off, 64);
      }
      if (n16 == 0) {
        ebuf[w * 128 + row] = e;
        zbuf[w * 128 + row] = z;
      }
    }
  }
  __syncthreads();

  float lsum = 0.f;
  if (t < 128) {
    float e = ebuf[t] + ebuf[128 + t] + ebuf[256 + t] + ebuf[384 + t];
    float z = zbuf[t] + zbuf[128 + t] + zbuf[256 + t] + zbuf[384 + t];
    lsum = logf(225.f + e) - z * (1.0f / 31.0f);
  }
#pragma unroll
  for (int off = 32; off > 0; off >>= 1) lsum += __shfl_down(lsum, off, 64);
  if (lane == 0 && lsum != 0.f) atomAddF(losssum, lsum);

  // ---- fused k6: last-block-out (replaces second grid barrier) ----
  // every wave drains its losssum atomic before the block barrier, so the
  // done-RMW globally follows all of this block's adds; the block whose RMW
  // returns 511 sees all 512 blocks' adds at the coherence point.
  asm volatile("s_waitcnt vmcnt(0)" ::: "memory");
  __syncthreads();
  if (t == 0) {
    unsigned a = __hip_atomic_fetch_add(&bars[4], 1u, __ATOMIC_RELAXED,
                                        __HIP_MEMORY_SCOPE_AGENT);
    if (a + 1u == 512u) {
      const float ls = __hip_atomic_load(losssum, __ATOMIC_RELAXED,
                                         __HIP_MEMORY_SCOPE_AGENT);
      out[0] = ls * (1.0f / (float)N2);
    }
  }
}

extern "C" void kernel_launch(void* const* d_in, const int* in_sizes, int n_in,
                              void* d_out, int out_size, void* d_ws, size_t ws_size,
                              hipStream_t stream) {
  const float* X = (const float*)d_in[0];
  const int* subject = (const int*)d_in[1];
  const int* labels = (const int*)d_in[2];
  char* ws = (char*)d_ws;
  ushort* Xb = (ushort*)(ws + OFF_XBF);
  float* partial = (float*)(ws + OFF_PART);
  ushort* centB = (ushort*)(ws + OFF_CENTB);
  float* xnorm = (float*)(ws + OFF_XNORM);
  int* perm = (int*)(ws + OFF_PERM);
  int* basep = (int*)(ws + OFF_BASE);
  int* offw = (int*)(ws + OFF_OFFW);
  int* counts = (int*)(ws + OFF_COUNTS);
  float* sumq = (float*)(ws + OFF_SUMQ);
  float* cnorm = (float*)(ws + OFF_CNORM);
  float* losssum = (float*)(ws + OFF_LOSS);
  unsigned* bars = (unsigned*)(ws + OFF_BARS);

  hipMemsetAsync(ws + ZERO_OFF, 0, ZERO_BYTES, stream);
  k0_all<<<32, 256, 0, stream>>>(subject, labels, counts, basep, offw, perm, bars);
  k1_sums<<<KN * SPLIT, 256, 0, stream>>>(X, perm, basep, Xb, partial, xnorm);
  k1b_cent<<<(KN * DN) / 256, 256, 0, stream>>>(partial, counts, centB, cnorm);
  k5_mfma<<<512, 256, 0, stream>>>(Xb, centB, subject, labels, xnorm, cnorm,
                                   counts, sumq, losssum, (float*)d_out, bars);
}

// Round 4
// 314.600 us; speedup vs baseline: 1.4776x; 1.2342x over previous
//
#include <hip/hip_runtime.h>
#include <math.h>

// Problem constants
#define BN 32768
#define DN 512
#define SN 32
#define LN 8
#define KN 256
#define N2 65536   // 2*BN
#define SPLIT 8    // blocks per group in k1/k3

typedef __attribute__((ext_vector_type(8))) short bf16x8;
typedef __attribute__((ext_vector_type(4))) float f32x4;

// workspace layout (byte offsets)
#define OFF_XBF     0ull            // ushort[N2*DN]            67108864
#define OFF_PART    67108864ull     // float[SPLIT*KN*DN]        4194304
#define OFF_CENTB   71303168ull     // ushort[KN*DN]              262144
#define OFF_PERM    71827456ull     // int[BN]                    131072
#define OFF_BASE    71958528ull     // int[KN+1]                    1028
#define OFF_OFFW    71959556ull     // int[KN]  (zero-based cursor) 1024
#define OFF_COUNTS  71960580ull     // int[KN]                      1024
#define OFF_SUMQ    71961604ull     // float[KN]                    1024
#define OFF_INVD    71962628ull     // float[KN]                    1024
#define OFF_LOSS    71963652ull     // float[1]                        4
#define OFF_BARS    71963656ull     // uint[6]: k0 {cnt,flag}, k3 done, k5 done
#define ZERO_OFF    OFF_OFFW
#define ZERO_BYTES  (71963680ull - OFF_OFFW)   // 4124

__device__ __forceinline__ float atomAddF(float* p, float v) {
  return unsafeAtomicAdd(p, v);   // hw global_atomic_add_f32 (coherence point)
}

// Relaxed grid barrier (k0 only: 32 blocks). All values crossing it are
// device-scope atomics read back with agent-scope loads -> no fences needed.
__device__ __forceinline__ void gridbar_relaxed(unsigned* cnt, unsigned* flag,
                                                unsigned nblocks) {
  asm volatile("s_waitcnt vmcnt(0)" ::: "memory");
  __syncthreads();
  if (threadIdx.x == 0) {
    unsigned a = __hip_atomic_fetch_add(cnt, 1u, __ATOMIC_RELAXED,
                                        __HIP_MEMORY_SCOPE_AGENT);
    if (a + 1u == nblocks) {
      __hip_atomic_store(flag, 1u, __ATOMIC_RELAXED, __HIP_MEMORY_SCOPE_AGENT);
    } else {
      while (!__hip_atomic_load(flag, __ATOMIC_RELAXED, __HIP_MEMORY_SCOPE_AGENT))
        __builtin_amdgcn_s_sleep(16);
    }
  }
  __syncthreads();
}

__device__ __forceinline__ ushort f2bf(float x) {
  union { float f; unsigned u; } v; v.f = x;
  unsigned u = v.u;
  unsigned r = (u + 0x7fffu + ((u >> 16) & 1u)) >> 16;  // RNE
  return (ushort)r;
}

__device__ __forceinline__ float bf2f(ushort x) {
  union { unsigned u; float f; } v; v.u = ((unsigned)x) << 16;
  return v.f;
}

// async 16B/lane global->LDS DMA (lands at lds base + lane*16)
__device__ __forceinline__ void async16(const void* g, void* l) {
  __builtin_amdgcn_global_load_lds(
      (const __attribute__((address_space(1))) unsigned int*)g,
      (__attribute__((address_space(3))) unsigned int*)l, 16, 0, 0);
}

// ---- k0: fused gid/hist + scan + scatter (32 blocks, relaxed grid-barrier) ----
// R3-verified.
__global__ __launch_bounds__(256) void k0_all(const int* __restrict__ subject,
    const int* __restrict__ labels, int* __restrict__ counts, int* __restrict__ base,
    int* __restrict__ offw, int* __restrict__ perm, unsigned* __restrict__ bars) {
  __shared__ int lhist[KN];
  __shared__ int sh[KN];
  __shared__ int lbase[KN];
  const int t = threadIdx.x;
  const int b0 = blockIdx.x * 1024;
  lhist[t] = 0;
  __syncthreads();
  int g[4], lr[4];
#pragma unroll
  for (int k = 0; k < 4; ++k) {
    const int b = b0 + k * 256 + t;
    g[k] = subject[b] * LN + labels[b];
    lr[k] = atomicAdd(&lhist[g[k]], 1);
  }
  __syncthreads();
  const int h = lhist[t];
  if (h) atomicAdd(&counts[t], 2 * h);
  gridbar_relaxed(&bars[0], &bars[1], 32);
  const int rows = ((int)__hip_atomic_load((unsigned*)&counts[t], __ATOMIC_RELAXED,
                                           __HIP_MEMORY_SCOPE_AGENT)) >> 1;
  sh[t] = rows;
  __syncthreads();
  for (int d = 1; d < 256; d <<= 1) {
    int add = (t >= d) ? sh[t - d] : 0;
    __syncthreads();
    sh[t] += add;
    __syncthreads();
  }
  const int excl = sh[t] - rows;
  if (blockIdx.x == 0) {
    base[t] = excl;
    if (t == 255) base[256] = sh[255];
  }
  if (h) lbase[t] = excl + atomicAdd(&offw[t], h);
  __syncthreads();
#pragma unroll
  for (int k = 0; k < 4; ++k)
    perm[lbase[g[k]] + lr[k]] = b0 + k * 256 + t;
}

// ---- k1: sorted segment-reduce group sums + f32->bf16 conversion ----
// Baseline-proven form (no xnorm). Each wave owns an independent row stream.
__global__ __launch_bounds__(256) void k1_sums(const float* __restrict__ X,
    const int* __restrict__ perm, const int* __restrict__ base,
    ushort* __restrict__ Xb, float* __restrict__ partial) {
  __shared__ float buf[4 * 512];
  const int g = blockIdx.x >> 3;
  const int s = blockIdx.x & (SPLIT - 1);
  const int t = threadIdx.x;
  const int w = t >> 6;
  const int lane = t & 63;
  const int start = base[g], end = base[g + 1];
  const int vs = s * 4 + w;              // stream 0..31

  float4 a0 = {0.f, 0.f, 0.f, 0.f};
  float4 a1 = {0.f, 0.f, 0.f, 0.f};

  int i = start + vs;
  if (i < end) {
    int idx = perm[i];
    const float* bp = X + (size_t)idx * 1024 + lane * 4;
    float4 x0 = *(const float4*)(bp);
    float4 x1 = *(const float4*)(bp + 256);
    float4 x2 = *(const float4*)(bp + 512);
    float4 x3 = *(const float4*)(bp + 768);
    while (true) {
      const int inext = i + 32;
      int idxn = idx;
      float4 y0 = x0, y1 = x1, y2 = x2, y3 = x3;
      if (inext < end) {
        idxn = perm[inext];
        const float* bn = X + (size_t)idxn * 1024 + lane * 4;
        y0 = *(const float4*)(bn);
        y1 = *(const float4*)(bn + 256);
        y2 = *(const float4*)(bn + 512);
        y3 = *(const float4*)(bn + 768);
      }
      a0.x += x0.x + x2.x; a0.y += x0.y + x2.y;
      a0.z += x0.z + x2.z; a0.w += x0.w + x2.w;
      a1.x += x1.x + x3.x; a1.y += x1.y + x3.y;
      a1.z += x1.z + x3.z; a1.w += x1.w + x3.w;
      ushort* xb0 = Xb + (size_t)idx * DN + lane * 4;
      ushort* xb1 = Xb + (size_t)(idx + BN) * DN + lane * 4;
      *(ushort4*)(xb0)       = (ushort4){f2bf(x0.x), f2bf(x0.y), f2bf(x0.z), f2bf(x0.w)};
      *(ushort4*)(xb0 + 256) = (ushort4){f2bf(x1.x), f2bf(x1.y), f2bf(x1.z), f2bf(x1.w)};
      *(ushort4*)(xb1)       = (ushort4){f2bf(x2.x), f2bf(x2.y), f2bf(x2.z), f2bf(x2.w)};
      *(ushort4*)(xb1 + 256) = (ushort4){f2bf(x3.x), f2bf(x3.y), f2bf(x3.z), f2bf(x3.w)};
      if (inext >= end) break;
      i = inext; idx = idxn; x0 = y0; x1 = y1; x2 = y2; x3 = y3;
    }
  }
  *(float4*)&buf[w * 512 + lane * 4] = a0;
  *(float4*)&buf[w * 512 + 256 + lane * 4] = a1;
  __syncthreads();
  if (t < 128) {
    float4 r = {0.f, 0.f, 0.f, 0.f};
#pragma unroll
    for (int ww = 0; ww < 4; ++ww) {
      float4 v = *(float4*)&buf[ww * 512 + t * 4];
      r.x += v.x; r.y += v.y; r.z += v.z; r.w += v.w;
    }
    *(float4*)&partial[((size_t)s * KN + g) * DN + t * 4] = r;
  }
}

// ---- k1b: reduce split partials -> bf16 centroids ----
__global__ __launch_bounds__(256) void k1b_cent(const float* __restrict__ partial,
    const int* __restrict__ counts, ushort* __restrict__ centB) {
  const int i = blockIdx.x * 256 + threadIdx.x;   // over KN*DN, [g][d]
  const int g = i >> 9;
  float ss = 0.f;
#pragma unroll
  for (int s = 0; s < SPLIT; ++s) ss += partial[(size_t)s * (KN * DN) + i];
  centB[i] = f2bf(ss / (float)counts[g]);
}

// ---- k3: group-per-block dist^(1/4) accumulation vs bf16 centroid,
//          + fused k4 density via last-block-out election ----
// diff^2 against bf16 centroid: numerics verified in R2/R3 (absmax 0.0).
__global__ __launch_bounds__(256) void k3_dist(const ushort* __restrict__ Xb,
    const int* __restrict__ perm, const int* __restrict__ base,
    const ushort* __restrict__ centB, const int* __restrict__ counts,
    float* __restrict__ sumq, float* __restrict__ invd,
    unsigned* __restrict__ bars) {
  __shared__ float wacc[4];
  __shared__ unsigned elect;
  __shared__ float sv[256];
  __shared__ float stv[256];
  const int g = blockIdx.x >> 3;
  const int s = blockIdx.x & (SPLIT - 1);
  const int t = threadIdx.x;
  const int w = t >> 6;
  const int lane = t & 63;
  const int start = base[g], end = base[g + 1];
  const int nviews = 2 * (end - start);
  const ushort* cp = centB + g * DN + lane * 8;
  float cs[8];
#pragma unroll
  for (int k = 0; k < 8; ++k) cs[k] = bf2f(cp[k]);
  float q = 0.f;
  const int vs = s * 4 + w;   // virtual split 0..31
  for (int j = vs; j < nviews; j += SPLIT * 4) {
    const int idx = perm[start + (j >> 1)];
    const int row = idx + (j & 1) * BN;
    int4 chunk = *(const int4*)(Xb + (size_t)row * DN + lane * 8);
    const ushort* us = (const ushort*)&chunk;
    float ss = 0.f;
#pragma unroll
    for (int k = 0; k < 8; ++k) {
      float diff = bf2f(us[k]) - cs[k];
      ss += diff * diff;
    }
#pragma unroll
    for (int off = 32; off > 0; off >>= 1) ss += __shfl_down(ss, off, 64);
    if (lane == 0) q += sqrtf(sqrtf(ss));
  }
  if (lane == 0) wacc[w] = q;
  __syncthreads();
  if (t == 0) atomAddF(&sumq[g], wacc[0] + wacc[1] + wacc[2] + wacc[3]);

  // ---- last-block-out election: the final block runs k4 (density) ----
  asm volatile("s_waitcnt vmcnt(0)" ::: "memory");   // all waves drain atomics
  __syncthreads();
  if (t == 0) {
    unsigned a = __hip_atomic_fetch_add(&bars[2], 1u, __ATOMIC_RELAXED,
                                        __HIP_MEMORY_SCOPE_AGENT);
    elect = (a + 1u == (unsigned)(KN * SPLIT)) ? 1u : 0u;
  }
  __syncthreads();
  if (!elect) return;

  // ---- k4 body (block-uniform branch; verified R3 logic) ----
  const int cnt = counts[t];
  const bool valid = cnt > 1;
  const float sq = __hip_atomic_load(&sumq[t], __ATOMIC_RELAXED,
                                     __HIP_MEMORY_SCOPE_AGENT);
  float dens = 0.f;
  if (valid) dens = (sq / (float)cnt) / logf((float)cnt + 10.f);
  sv[t] = valid ? dens : -INFINITY;
  __syncthreads();
  for (int s2 = 128; s2 > 0; s2 >>= 1) {
    if (t < s2) sv[t] = fmaxf(sv[t], sv[t + s2]);
    __syncthreads();
  }
  const float dmax = sv[0];
  __syncthreads();
  const float d0 = valid ? dens : dmax;
  sv[t] = d0;
  __syncthreads();
  int rank = 0;
  for (int j = 0; j < 256; ++j) {
    float vj = sv[j];
    rank += (vj < d0) || (vj == d0 && j < t);
  }
  stv[rank] = d0;
  __syncthreads();
  const float q10 = 0.5f * (stv[25] + stv[26]);
  const float q90 = 0.5f * (stv[229] + stv[230]);
  const float dc = fminf(fmaxf(d0, q10), q90);
  sv[t] = dc;
  __syncthreads();
  for (int s2 = 128; s2 > 0; s2 >>= 1) {
    if (t < s2) sv[t] += sv[t + s2];
    __syncthreads();
  }
  invd[t] = (sv[0] * (1.0f / 256.f)) / (0.1f * dc);
}

// ---- k5: MFMA GEMM (baseline-proven) + fused softmax loss + final mean ----
// NOTE: (256,2) is required — (256,3) caps VGPRs < 128 acc + staging (spills).
#define TAB (128 * 128)   // A tile bytes
#define TBB (256 * 128)   // B tile bytes
__global__ __launch_bounds__(256, 2) void k5_mfma(const ushort* __restrict__ Xb,
    const ushort* __restrict__ centB, const int* __restrict__ subject,
    const int* __restrict__ labels, const float* __restrict__ invd,
    float* __restrict__ losssum, float* __restrict__ out,
    unsigned* __restrict__ bars) {
  __shared__ char smem[TAB + TBB + 1024];
  char* ldsA = smem;                 // [128 rows][128B, swizzled]
  char* ldsB = smem + TAB;           // [256 rows][128B, swizzled]
  float* maxbuf = (float*)smem;      // epilogue aliases ldsA: [4][128]
  float* gmax = (float*)(smem + 2048);    // [128]
  float* ebuf = (float*)(smem + 2560);    // [4][128]
  float* zbuf = (float*)(smem + 4608);    // [4][128]
  int* labs = (int*)(smem + TAB + TBB);
  int* subs = labs + 128;

  const int t = threadIdx.x;
  const int w = t >> 6;
  const int lane = t & 63;
  const int quad = lane >> 4;
  const int n16 = lane & 15;
  const int li = lane >> 3;          // row within an 8-row DMA chunk
  const int lc = lane & 7;           // lds slot chunk
  const int srcc = lc ^ li;          // swizzled source chunk
  const int rowbase = blockIdx.x * 128;

  if (t < 128) {
    int b = (rowbase + t) & (BN - 1);
    labs[t] = labels[b];
    subs[t] = subject[b];
  }

  f32x4 acc[8][4];
#pragma unroll
  for (int mt = 0; mt < 8; ++mt)
#pragma unroll
    for (int nt = 0; nt < 4; ++nt) acc[mt][nt] = (f32x4){0.f, 0.f, 0.f, 0.f};

  const ushort* Arow = Xb + (size_t)rowbase * DN;

  for (int k0 = 0; k0 < DN; k0 += 64) {
    __syncthreads();
#pragma unroll
    for (int q = 0; q < 4; ++q) {
      const int r0 = w * 32 + q * 8;
      async16(Arow + (size_t)(r0 + li) * DN + k0 + srcc * 8, ldsA + r0 * 128);
    }
#pragma unroll
    for (int q = 0; q < 8; ++q) {
      const int g0 = w * 64 + q * 8;
      async16(centB + (size_t)(g0 + li) * DN + k0 + srcc * 8, ldsB + g0 * 128);
    }
    __syncthreads();
#pragma unroll
    for (int s = 0; s < 2; ++s) {
      const int csw = ((s * 4 + quad) ^ (n16 & 7)) * 16;
      bf16x8 bfr[4];
#pragma unroll
      for (int nt = 0; nt < 4; ++nt) {
        int g = w * 64 + nt * 16 + n16;
        bfr[nt] = *(bf16x8*)(ldsB + g * 128 + csw);
      }
#pragma unroll
      for (int mt = 0; mt < 8; ++mt) {
        bf16x8 afr = *(bf16x8*)(ldsA + (mt * 16 + n16) * 128 + csw);
#pragma unroll
        for (int nt = 0; nt < 4; ++nt)
          acc[mt][nt] = __builtin_amdgcn_mfma_f32_16x16x32_bf16(afr, bfr[nt], acc[mt][nt], 0, 0, 0);
      }
    }
  }

  float iv[4];
#pragma unroll
  for (int nt = 0; nt < 4; ++nt) iv[nt] = invd[w * 64 + nt * 16 + n16];

  __syncthreads();

#pragma unroll
  for (int mt = 0; mt < 8; ++mt) {
#pragma unroll
    for (int r = 0; r < 4; ++r) {
      float mm = -INFINITY;
#pragma unroll
      for (int nt = 0; nt < 4; ++nt) mm = fmaxf(mm, acc[mt][nt][r] * iv[nt]);
#pragma unroll
      for (int off = 1; off < 16; off <<= 1) mm = fmaxf(mm, __shfl_xor(mm, off, 64));
      if (n16 == 0) maxbuf[w * 128 + mt * 16 + quad * 4 + r] = mm;
    }
  }
  __syncthreads();
  if (t < 128)
    gmax[t] = fmaxf(fmaxf(maxbuf[t], maxbuf[128 + t]),
                    fmaxf(maxbuf[256 + t], maxbuf[384 + t]));
  __syncthreads();

#pragma unroll
  for (int mt = 0; mt < 8; ++mt) {
#pragma unroll
    for (int r = 0; r < 4; ++r) {
      const int row = mt * 16 + quad * 4 + r;
      const float gm = gmax[row];
      const int lab = labs[row];
      const int sub = subs[row];
      float e = 0.f, z = 0.f;
      if ((n16 & 7) == lab) {
#pragma unroll
        for (int nt = 0; nt < 4; ++nt) {
          int gdiv8 = w * 8 + nt * 2 + (n16 >> 3);
          if (gdiv8 != sub) {
            float svv = acc[mt][nt][r] * iv[nt] - gm;
            e += expf(svv);
            z += svv;
          }
        }
      }
#pragma unroll
      for (int off = 1; off < 16; off <<= 1) {
        e += __shfl_xor(e, off, 64);
        z += __shfl_xor(z, off, 64);
      }
      if (n16 == 0) {
        ebuf[w * 128 + row] = e;
        zbuf[w * 128 + row] = z;
      }
    }
  }
  __syncthreads();

  float lsum = 0.f;
  if (t < 128) {
    float e = ebuf[t] + ebuf[128 + t] + ebuf[256 + t] + ebuf[384 + t];
    float z = zbuf[t] + zbuf[128 + t] + zbuf[256 + t] + zbuf[384 + t];
    lsum = logf(225.f + e) - z * (1.0f / 31.0f);
  }
#pragma unroll
  for (int off = 32; off > 0; off >>= 1) lsum += __shfl_down(lsum, off, 64);
  if (lane == 0 && lsum != 0.f) atomAddF(losssum, lsum);

  // ---- fused k6: last-block-out final mean (R3-verified pattern) ----
  asm volatile("s_waitcnt vmcnt(0)" ::: "memory");
  __syncthreads();
  if (t == 0) {
    unsigned a = __hip_atomic_fetch_add(&bars[4], 1u, __ATOMIC_RELAXED,
                                        __HIP_MEMORY_SCOPE_AGENT);
    if (a + 1u == (unsigned)(N2 / 128)) {
      const float ls = __hip_atomic_load(losssum, __ATOMIC_RELAXED,
                                         __HIP_MEMORY_SCOPE_AGENT);
      out[0] = ls * (1.0f / (float)N2);
    }
  }
}

extern "C" void kernel_launch(void* const* d_in, const int* in_sizes, int n_in,
                              void* d_out, int out_size, void* d_ws, size_t ws_size,
                              hipStream_t stream) {
  const float* X = (const float*)d_in[0];
  const int* subject = (const int*)d_in[1];
  const int* labels = (const int*)d_in[2];
  char* ws = (char*)d_ws;
  ushort* Xb = (ushort*)(ws + OFF_XBF);
  float* partial = (float*)(ws + OFF_PART);
  ushort* centB = (ushort*)(ws + OFF_CENTB);
  int* perm = (int*)(ws + OFF_PERM);
  int* basep = (int*)(ws + OFF_BASE);
  int* offw = (int*)(ws + OFF_OFFW);
  int* counts = (int*)(ws + OFF_COUNTS);
  float* sumq = (float*)(ws + OFF_SUMQ);
  float* invd = (float*)(ws + OFF_INVD);
  float* losssum = (float*)(ws + OFF_LOSS);
  unsigned* bars = (unsigned*)(ws + OFF_BARS);

  hipMemsetAsync(ws + ZERO_OFF, 0, ZERO_BYTES, stream);
  k0_all<<<32, 256, 0, stream>>>(subject, labels, counts, basep, offw, perm, bars);
  k1_sums<<<KN * SPLIT, 256, 0, stream>>>(X, perm, basep, Xb, partial);
  k1b_cent<<<(KN * DN) / 256, 256, 0, stream>>>(partial, counts, centB);
  k3_dist<<<KN * SPLIT, 256, 0, stream>>>(Xb, perm, basep, centB, counts,
                                          sumq, invd, bars);
  k5_mfma<<<N2 / 128, 256, 0, stream>>>(Xb, centB, subject, labels, invd,
                                        losssum, (float*)d_out, bars);
}